// Round 15
// baseline (247.284 us; speedup 1.0000x reference)
//
#include <hip/hip_runtime.h>
#include <math.h>

// B=32 graphs, N=1024 nodes, D=128 in-dim, C=64 out-dim, K=16.
#define OUT_ELEMS 2097152   // 32768*64
#define EDGE_ELEMS 524288   // 32*1024*16
#define CL_WS_BYTES (32768ull * 128ull * 4ull)  // 16 MiB candidate lists
#define NC_WS_BYTES (32768ull * 4ull)           // 128 KiB counts
#define WS_NEED (CL_WS_BYTES + NC_WS_BYTES)

__device__ __forceinline__ unsigned int rotl32(unsigned int x, int r){
  return (x << r) | (x >> (32 - r));
}

// JAX partitionable threefry, key (0,1): counter = (0, e); out = o0 ^ o1.
__device__ __forceinline__ unsigned int tf_bits_part(unsigned int e){
  unsigned int x0 = 0u, x1 = e;
  const unsigned int ks1 = 1u;
  const unsigned int ks2 = 0x1BD11BDBu;
  x1 += ks1;
#define TFR(r) { x0 += x1; x1 = rotl32(x1, r); x1 ^= x0; }
  TFR(13) TFR(15) TFR(26) TFR(6)
  x0 += ks1; x1 += ks2 + 1u;
  TFR(17) TFR(29) TFR(16) TFR(24)
  x0 += ks2; x1 += 0u + 2u;
  TFR(13) TFR(15) TFR(26) TFR(6)
  x0 += 0u;  x1 += ks1 + 3u;
  TFR(17) TFR(29) TFR(16) TFR(24)
  x0 += ks1; x1 += ks2 + 4u;
  TFR(13) TFR(15) TFR(26) TFR(6)
  x0 += ks2; x1 += 0u + 5u;
#undef TFR
  return x0 ^ x1;
}

// hardware f64 reciprocal + 2 Newton steps: rel err ~1e-16.
__device__ __forceinline__ double rcp64(double x){
  double r;
  asm("v_rcp_f64 %0, %1" : "=v"(r) : "v"(x));
  double e = fma(-x, r, 1.0); r = fma(r, e, r);
  e = fma(-x, r, 1.0); r = fma(r, e, r);
  return r;
}

// fast e^x for x in [-740, ~1]; rel err ~2e-11 (deg-9).
__device__ __forceinline__ double fast_exp(double x){
  double fn = __builtin_rint(x * 1.4426950408889634);
  int n = (int)fn;
  double r = fma(fn, -0.6931471803691238, x);
  r = fma(fn, -1.9082149292705877e-10, r);
  double p = 2.7557319223985893e-06;
  p = fma(r, p, 2.4801587301587302e-05);
  p = fma(r, p, 1.9841269841269841e-04);
  p = fma(r, p, 1.3888888888888889e-03);
  p = fma(r, p, 8.3333333333333333e-03);
  p = fma(r, p, 4.1666666666666664e-02);
  p = fma(r, p, 1.6666666666666666e-01);
  p = fma(r, p, 0.5);
  p = fma(r, p, 1.0);
  p = fma(r, p, 1.0);
  double scale = __longlong_as_double(((long long)(n + 1023)) << 52);
  return p * scale;
}

// fast ln(x), normal positive x; atanh form; abs err ~2e-11.
__device__ __forceinline__ double fast_log(double x){
  long long bx = __double_as_longlong(x);
  long long e = (bx >> 52) - 1023;
  double m = __longlong_as_double((bx & 0xFFFFFFFFFFFFFll) |
                                  0x3FF0000000000000ll);
  int big = m > 1.4142135623730951;
  m = big ? 0.5 * m : m;
  e += big;
  double s = (m - 1.0) * rcp64(m + 1.0);
  double s2 = s * s;
  double p = fma(s2, 2.0/11.0, 2.0/9.0);
  p = fma(s2, p, 2.0/7.0);
  p = fma(s2, p, 2.0/5.0);
  p = fma(s2, p, 2.0/3.0);
  double lm = fma(s * s2, p, 2.0 * s);
  return fma((double)e, 0.6931471805599453, lm);
}

// Exact f64 score of candidate jc. Accumulation order q=0..63 sequential —
// bit-identical to v5..v10. unroll 4: only 4 float4 loads in flight.
__device__ __forceinline__ unsigned long long score_cand(
    const float* __restrict__ og, const double* __restrict__ hrow,
    unsigned int jc, unsigned int base, double Td, bool act){
  const float4* cp4 = (const float4*)(og + ((size_t)jc << 6));
  double acc = 0.0;
  #pragma unroll 4
  for (int ch = 0; ch < 16; ++ch){
    float4 cf = cp4[ch];
    double d0 = hrow[(ch << 2) + 0] - (double)cf.x;
    double d1 = hrow[(ch << 2) + 1] - (double)cf.y;
    double d2 = hrow[(ch << 2) + 2] - (double)cf.z;
    double d3 = hrow[(ch << 2) + 3] - (double)cf.w;
    acc = fma(d0, d0, acc);
    acc = fma(d1, d1, acc);
    acc = fma(d2, d2, acc);
    acc = fma(d3, d3, acc);
  }
  if (!act) return 0ull;
  double sgm = fast_exp(-Td * acc);
  unsigned int bits = tf_bits_part(base | jc);
  float f = __uint_as_float(0x3f800000u | (bits >> 9)) - 1.0f;
  double u = (f > 0.0f) ? (double)f : 1.1754943508222875e-38;
  double w = -fast_log(u);
  double z = -fast_log(w);
  double sc = sgm + z;
  unsigned long long kb = (unsigned long long)__double_as_longlong(sc);
  kb ^= (unsigned long long)(((long long)kb) >> 63) | 0x8000000000000000ull;
  return (kb & ~1023ull) | (unsigned long long)(1023u - jc);
}

// Full descending bitonic sort of u64 keys across 64 lanes.
__device__ __forceinline__ unsigned long long bitonic64_desc(
    unsigned long long key, int lane){
  #pragma unroll
  for (int k = 2; k <= 64; k <<= 1){
    #pragma unroll
    for (int j = k >> 1; j; j >>= 1){
      unsigned long long o = __shfl_xor(key, j, 64);
      bool keep_hi = ((lane & k) == 0) == ((lane & j) == 0);
      key = (keep_hi == (o > key)) ? o : key;
    }
  }
  return key;
}

// Full descending bitonic sort of u32 keys across 64 lanes.
__device__ __forceinline__ unsigned int bitonic32_desc(
    unsigned int key, int lane){
  #pragma unroll
  for (int k = 2; k <= 64; k <<= 1){
    #pragma unroll
    for (int j = k >> 1; j; j >>= 1){
      unsigned int o = __shfl_xor(key, j, 64);
      bool keep_hi = ((lane & k) == 0) == ((lane & j) == 0);
      key = (keep_hi == (o > key)) ? o : key;
    }
  }
  return key;
}

// Per-wave edges phases 1-3 for one row: threefry bits, lane-max bitonic
// cut, compaction into clrow[0..127] (any address space). Returns nc.
template<typename P>
__device__ __forceinline__ int phase123(
    unsigned int base, int lane, P* clrow){
  unsigned int v[16];
  unsigned int pmax = 0u;
  #pragma unroll
  for (int m = 0; m < 16; ++m){
    const unsigned int j = (unsigned int)(m << 6) + (unsigned int)lane;
    unsigned int bits = tf_bits_part(base | j);
    v[m] = (bits & ~1023u) | (1023u - j);
    pmax = (v[m] > pmax) ? v[m] : pmax;
  }
  unsigned int sorted = bitonic32_desc(pmax, lane);
  unsigned int b16p = __shfl(sorted, 15, 64);
  float u16 = __uint_as_float(0x3f800000u | (b16p >> 9)) - 1.0f;
  float z16 = -__logf(-__logf(u16));
  float uc  = __expf(-__expf(-(z16 - 1.001f)));
  unsigned int cp = ((__float_as_uint(1.0f + uc) & 0x7FFFFFu) << 9) & ~1023u;
  int cnt = 0;
  #pragma unroll
  for (int m = 0; m < 16; ++m) cnt += (v[m] >= cp) ? 1 : 0;
  int s = cnt;
  #pragma unroll
  for (int off = 1; off < 64; off <<= 1){
    int o = __shfl_up(s, off, 64);
    s += (lane >= off) ? o : 0;
  }
  int nc = __shfl(s, 63, 64);
  nc = (nc > 128) ? 128 : nc;
  int slot = s - cnt;
  #pragma unroll
  for (int m = 0; m < 16; ++m){
    if (v[m] >= cp && slot < 128){
      clrow[slot] = 1023u - (v[m] & 1023u);
      ++slot;
    }
  }
  return nc;
}

// Per-wave phase 4: exact f64 rescore of candidates + bitonic top-16.
__device__ __forceinline__ void phase4(
    const float* __restrict__ og, const double* __restrict__ hrow,
    unsigned int jc1, unsigned int jc2, bool act1, bool act2, int nc,
    unsigned int base, double Td, int gb, int grow, int lane,
    float* __restrict__ rows_out, float* __restrict__ cols_out){
  unsigned long long key = score_cand(og, hrow, jc1, base, Td, act1);
  key = bitonic64_desc(key, lane);
  if (nc > 64){
    unsigned long long k2 = score_cand(og, hrow, jc2, base, Td, act2);
    k2 = bitonic64_desc(k2, lane);
    unsigned long long kr = __shfl(k2, 63 - lane, 64);
    key = (kr > key) ? kr : key;
    #pragma unroll
    for (int j = 32; j; j >>= 1){
      unsigned long long o = __shfl_xor(key, j, 64);
      bool left = (lane & j) == 0;
      bool take = left ? (o > key) : (o < key);
      key = take ? o : key;
    }
  }
  if (lane < 16){
    rows_out[((size_t)grow << 4) + lane] = (float)grow;
    cols_out[((size_t)grow << 4) + lane] =
        (float)((gb << 10) + (1023 - (int)(key & 1023ull)));
  }
}

// ---------------- kernel A: encoder + phases 1-3 ----------------
// 2048 blocks x 16 rows. Encoder: 4 f64 chains/thread, k-sequential, f32 LDS
// x-tile + exact per-k cvt -> bit-identical out (same sequence as v6..v10).
// Then p123 for the same 16 rows (independent of out), candidate lists to ws.
__global__ __launch_bounds__(256, 8) void encA_v12(
    const float* __restrict__ x, const float* __restrict__ W,
    const float* __restrict__ b, float* __restrict__ out,
    unsigned int* __restrict__ cl_ws, int* __restrict__ nc_ws){
  __shared__ float xs[2048];            // 16 rows x 128 = 8 KB
  const int tid = threadIdx.x, wave = tid >> 6, lane = tid & 63;
  const int bid = blockIdx.x;
  const size_t r0 = (size_t)bid << 4;        // first global row
  const int gb = bid >> 6;                   // graph (64 blocks per graph)
  const int lr0 = (bid & 63) << 4;           // first graph-local row

  { // stage x tile
    const float4* xg4 = (const float4*)(x + (r0 << 7));
    float4* xs4 = (float4*)xs;
    xs4[tid] = xg4[tid];
    xs4[tid + 256] = xg4[tid + 256];
  }
  __syncthreads();

  { // encoder: wave w -> local rows w*4..w*4+3, lane = column c
    double acc[4];
    const double bc = (double)b[lane];
    #pragma unroll
    for (int i = 0; i < 4; ++i) acc[i] = bc;
    #pragma unroll 4
    for (int k = 0; k < 128; k += 4){
      const double w0 = (double)W[((k + 0) << 6) + lane];
      const double w1 = (double)W[((k + 1) << 6) + lane];
      const double w2 = (double)W[((k + 2) << 6) + lane];
      const double w3 = (double)W[((k + 3) << 6) + lane];
      #pragma unroll
      for (int i = 0; i < 4; ++i){
        const float4 xv = *(const float4*)&xs[(((wave << 2) + i) << 7) + k];
        acc[i] = fma((double)xv.x, w0, acc[i]);
        acc[i] = fma((double)xv.y, w1, acc[i]);
        acc[i] = fma((double)xv.z, w2, acc[i]);
        acc[i] = fma((double)xv.w, w3, acc[i]);
      }
    }
    #pragma unroll
    for (int i = 0; i < 4; ++i)
      out[((r0 + (wave << 2) + i) << 6) + lane] = (float)acc[i];
  }

  // phases 1-3 for local rows wave*4 .. wave*4+3 (no dependency on out)
  #pragma unroll 1
  for (int rr = 0; rr < 4; ++rr){
    const int lrow = (wave << 2) + rr;
    const int grow = (int)r0 + lrow;
    const unsigned int base =
        ((unsigned int)gb << 20) | ((unsigned int)(lr0 + lrow) << 10);
    int nc = phase123(base, lane, cl_ws + ((size_t)grow << 7));
    if (lane == 0) nc_ws[grow] = nc;
  }
}

// ---------------- kernel B: phase 4 only ----------------
// 8192 blocks x 4 row-waves. Reads candidate lists from ws (coalesced),
// exact f64 rescore + bitonic top-16. Math identical to v10.
__global__ __launch_bounds__(256, 8) void p4B_v12(
    const float* __restrict__ out32, const float* __restrict__ temp,
    const unsigned int* __restrict__ cl_ws, const int* __restrict__ nc_ws,
    float* __restrict__ rows_out, float* __restrict__ cols_out){
  __shared__ double hid[4][64];         // 2 KB
  const int tid = threadIdx.x, wave = tid >> 6, lane = tid & 63;
  const int gb = blockIdx.x >> 8;
  const int i0 = (blockIdx.x & 255) << 2;
  const int r  = i0 + wave;
  const int grow = (gb << 10) + r;
  const float* __restrict__ og = out32 + ((size_t)gb << 16);

  hid[wave][lane] = (double)og[((size_t)r << 6) + lane];
  const unsigned int base = ((unsigned int)gb << 20) | ((unsigned int)r << 10);
  const int nc = nc_ws[grow];
  const unsigned int* clg = cl_ws + ((size_t)grow << 7);
  const bool act1 = (lane < nc);
  const bool act2 = (64 + lane < nc);
  unsigned int jc1 = act1 ? clg[lane] : 0u;
  unsigned int jc2 = act2 ? clg[64 + lane] : 0u;
  const double Td = (double)temp[0];
  phase4(og, &hid[wave][0], jc1, jc2, act1, act2, nc, base, Td,
         gb, grow, lane, rows_out, cols_out);
}

// ---------------- proven fallback (round-13 v10 path) ----------------

__global__ __launch_bounds__(256) void encoder_v10(
    const float* __restrict__ x, const float* __restrict__ W,
    const float* __restrict__ b, float* __restrict__ out){
  __shared__ double xs64[8192];
  const int tid = threadIdx.x;
  const int w = tid >> 6, c = tid & 63;
  const size_t r0 = (size_t)blockIdx.x << 6;
  {
    const float4* xg4 = (const float4*)(x + (r0 << 7));
    #pragma unroll
    for (int s = 0; s < 8; ++s){
      const int idx = tid + (s << 8);
      float4 v = xg4[idx];
      double2 d0, d1;
      d0.x = (double)v.x; d0.y = (double)v.y;
      d1.x = (double)v.z; d1.y = (double)v.w;
      *(double2*)&xs64[(idx << 2) + 0] = d0;
      *(double2*)&xs64[(idx << 2) + 2] = d1;
    }
  }
  __syncthreads();
  double acc[16];
  const double bc = (double)b[c];
  #pragma unroll
  for (int i = 0; i < 16; ++i) acc[i] = bc;
  #pragma unroll 4
  for (int k = 0; k < 128; k += 4){
    const double w0 = (double)W[((k + 0) << 6) + c];
    const double w1 = (double)W[((k + 1) << 6) + c];
    const double w2 = (double)W[((k + 2) << 6) + c];
    const double w3 = (double)W[((k + 3) << 6) + c];
    #pragma unroll
    for (int i = 0; i < 16; ++i){
      const double2 xa = *(const double2*)&xs64[(((w << 4) + i) << 7) + k];
      const double2 xb = *(const double2*)&xs64[(((w << 4) + i) << 7) + k + 2];
      acc[i] = fma(xa.x, w0, acc[i]);
      acc[i] = fma(xa.y, w1, acc[i]);
      acc[i] = fma(xb.x, w2, acc[i]);
      acc[i] = fma(xb.y, w3, acc[i]);
    }
  }
  #pragma unroll
  for (int i = 0; i < 16; ++i)
    out[((r0 + (w << 4) + i) << 6) + c] = (float)acc[i];
}

__global__ __launch_bounds__(256, 8) void edges_v10(
    const float* __restrict__ out32, const float* __restrict__ temp,
    float* __restrict__ rows_out, float* __restrict__ cols_out){
  __shared__ double hid[4][64];
  __shared__ unsigned int cl[4][128];
  __shared__ int ncA[4];
  const int tid = threadIdx.x, wave = tid >> 6, lane = tid & 63;
  const int gb = blockIdx.x >> 8;
  const int i0 = (blockIdx.x & 255) << 2;
  const int r  = i0 + wave;
  const float* __restrict__ og = out32 + ((size_t)gb << 16);

  hid[wave][lane] = (double)og[((size_t)r << 6) + lane];
  const unsigned int base = ((unsigned int)gb << 20) | ((unsigned int)r << 10);
  int nc = phase123(base, lane, &cl[wave][0]);
  if (lane == 0) ncA[wave] = nc;
  const double Td = (double)temp[0];
  const int grow = (gb << 10) + r;
  const int ncw = ncA[wave];
  const bool act1 = (lane < ncw);
  const bool act2 = (64 + lane < ncw);
  unsigned int jc1 = act1 ? cl[wave][lane] : 0u;
  unsigned int jc2 = act2 ? cl[wave][64 + lane] : 0u;
  phase4(og, &hid[wave][0], jc1, jc2, act1, act2, ncw, base, Td,
         gb, grow, lane, rows_out, cols_out);
}

extern "C" void kernel_launch(void* const* d_in, const int* in_sizes, int n_in,
                              void* d_out, int out_size, void* d_ws, size_t ws_size,
                              hipStream_t stream){
  const float* x = (const float*)d_in[0];
  const float* W = (const float*)d_in[1];
  const float* b = (const float*)d_in[2];
  const float* T = (const float*)d_in[3];
  float* out      = (float*)d_out;
  float* rows_out = out + OUT_ELEMS;
  float* cols_out = rows_out + EDGE_ELEMS;

  if (ws_size >= WS_NEED){
    unsigned int* cl_ws = (unsigned int*)d_ws;
    int* nc_ws = (int*)((char*)d_ws + CL_WS_BYTES);
    encA_v12<<<2048, 256, 0, stream>>>(x, W, b, out, cl_ws, nc_ws);
    p4B_v12<<<8192, 256, 0, stream>>>(out, T, cl_ws, nc_ws,
                                      rows_out, cols_out);
  } else {
    encoder_v10<<<512, 256, 0, stream>>>(x, W, b, out);
    edges_v10<<<8192, 256, 0, stream>>>(out, T, rows_out, cols_out);
  }
}

// Round 16
// 195.754 us; speedup vs baseline: 1.2632x; 1.2632x over previous
//
#include <hip/hip_runtime.h>
#include <math.h>

// B=32 graphs, N=1024 nodes, D=128 in-dim, C=64 out-dim, K=16.
#define OUT_ELEMS 2097152   // 32768*64
#define EDGE_ELEMS 524288   // 32*1024*16

#if defined(__has_builtin)
# if __has_builtin(__builtin_amdgcn_mfma_f64_16x16x4f64)
#  define HAVE_MFMA_F64 1
# endif
#endif

typedef double vdbl4 __attribute__((ext_vector_type(4)));

__device__ __forceinline__ unsigned int rotl32(unsigned int x, int r){
  return (x << r) | (x >> (32 - r));
}

// JAX partitionable threefry, key (0,1): counter = (0, e); out = o0 ^ o1.
__device__ __forceinline__ unsigned int tf_bits_part(unsigned int e){
  unsigned int x0 = 0u, x1 = e;
  const unsigned int ks1 = 1u;
  const unsigned int ks2 = 0x1BD11BDBu;
  x1 += ks1;
#define TFR(r) { x0 += x1; x1 = rotl32(x1, r); x1 ^= x0; }
  TFR(13) TFR(15) TFR(26) TFR(6)
  x0 += ks1; x1 += ks2 + 1u;
  TFR(17) TFR(29) TFR(16) TFR(24)
  x0 += ks2; x1 += 0u + 2u;
  TFR(13) TFR(15) TFR(26) TFR(6)
  x0 += 0u;  x1 += ks1 + 3u;
  TFR(17) TFR(29) TFR(16) TFR(24)
  x0 += ks1; x1 += ks2 + 4u;
  TFR(13) TFR(15) TFR(26) TFR(6)
  x0 += ks2; x1 += 0u + 5u;
#undef TFR
  return x0 ^ x1;
}

// hardware f64 reciprocal + 2 Newton steps: rel err ~1e-16.
__device__ __forceinline__ double rcp64(double x){
  double r;
  asm("v_rcp_f64 %0, %1" : "=v"(r) : "v"(x));
  double e = fma(-x, r, 1.0); r = fma(r, e, r);
  e = fma(-x, r, 1.0); r = fma(r, e, r);
  return r;
}

// fast e^x for x in [-740, ~1]; rel err ~2e-11 (deg-9).
__device__ __forceinline__ double fast_exp(double x){
  double fn = __builtin_rint(x * 1.4426950408889634);
  int n = (int)fn;
  double r = fma(fn, -0.6931471803691238, x);
  r = fma(fn, -1.9082149292705877e-10, r);
  double p = 2.7557319223985893e-06;
  p = fma(r, p, 2.4801587301587302e-05);
  p = fma(r, p, 1.9841269841269841e-04);
  p = fma(r, p, 1.3888888888888889e-03);
  p = fma(r, p, 8.3333333333333333e-03);
  p = fma(r, p, 4.1666666666666664e-02);
  p = fma(r, p, 1.6666666666666666e-01);
  p = fma(r, p, 0.5);
  p = fma(r, p, 1.0);
  p = fma(r, p, 1.0);
  double scale = __longlong_as_double(((long long)(n + 1023)) << 52);
  return p * scale;
}

// fast ln(x), normal positive x; atanh form; abs err ~2e-11.
__device__ __forceinline__ double fast_log(double x){
  long long bx = __double_as_longlong(x);
  long long e = (bx >> 52) - 1023;
  double m = __longlong_as_double((bx & 0xFFFFFFFFFFFFFll) |
                                  0x3FF0000000000000ll);
  int big = m > 1.4142135623730951;
  m = big ? 0.5 * m : m;
  e += big;
  double s = (m - 1.0) * rcp64(m + 1.0);
  double s2 = s * s;
  double p = fma(s2, 2.0/11.0, 2.0/9.0);
  p = fma(s2, p, 2.0/7.0);
  p = fma(s2, p, 2.0/5.0);
  p = fma(s2, p, 2.0/3.0);
  double lm = fma(s * s2, p, 2.0 * s);
  return fma((double)e, 0.6931471805599453, lm);
}

// Exact f64 score of candidate jc. Accumulation order q=0..63 sequential —
// bit-identical to v5..v10. unroll 4: only 4 float4 loads in flight.
__device__ __forceinline__ unsigned long long score_cand(
    const float* __restrict__ og, const double* __restrict__ hrow,
    unsigned int jc, unsigned int base, double Td, bool act){
  const float4* cp4 = (const float4*)(og + ((size_t)jc << 6));
  double acc = 0.0;
  #pragma unroll 4
  for (int ch = 0; ch < 16; ++ch){
    float4 cf = cp4[ch];
    double d0 = hrow[(ch << 2) + 0] - (double)cf.x;
    double d1 = hrow[(ch << 2) + 1] - (double)cf.y;
    double d2 = hrow[(ch << 2) + 2] - (double)cf.z;
    double d3 = hrow[(ch << 2) + 3] - (double)cf.w;
    acc = fma(d0, d0, acc);
    acc = fma(d1, d1, acc);
    acc = fma(d2, d2, acc);
    acc = fma(d3, d3, acc);
  }
  if (!act) return 0ull;
  double sgm = fast_exp(-Td * acc);
  unsigned int bits = tf_bits_part(base | jc);
  float f = __uint_as_float(0x3f800000u | (bits >> 9)) - 1.0f;
  double u = (f > 0.0f) ? (double)f : 1.1754943508222875e-38;
  double w = -fast_log(u);
  double z = -fast_log(w);
  double sc = sgm + z;
  unsigned long long kb = (unsigned long long)__double_as_longlong(sc);
  kb ^= (unsigned long long)(((long long)kb) >> 63) | 0x8000000000000000ull;
  return (kb & ~1023ull) | (unsigned long long)(1023u - jc);
}

// Full descending bitonic sort of u64 keys across 64 lanes.
__device__ __forceinline__ unsigned long long bitonic64_desc(
    unsigned long long key, int lane){
  #pragma unroll
  for (int k = 2; k <= 64; k <<= 1){
    #pragma unroll
    for (int j = k >> 1; j; j >>= 1){
      unsigned long long o = __shfl_xor(key, j, 64);
      bool keep_hi = ((lane & k) == 0) == ((lane & j) == 0);
      key = (keep_hi == (o > key)) ? o : key;
    }
  }
  return key;
}

// Full descending bitonic sort of u32 keys across 64 lanes.
__device__ __forceinline__ unsigned int bitonic32_desc(
    unsigned int key, int lane){
  #pragma unroll
  for (int k = 2; k <= 64; k <<= 1){
    #pragma unroll
    for (int j = k >> 1; j; j >>= 1){
      unsigned int o = __shfl_xor(key, j, 64);
      bool keep_hi = ((lane & k) == 0) == ((lane & j) == 0);
      key = (keep_hi == (o > key)) ? o : key;
    }
  }
  return key;
}

#ifdef HAVE_MFMA_F64
// ---------------- encoder via f64 MFMA ----------------
// 2048 blocks x 16 rows. One 16x16 col-tile per wave, K=128 as 32 chained
// v_mfma_f64_16x16x4. Accumulation-order change vs k-sequential is ~1e-16
// relative (f32-rounding flip prob ~1e-9/elem — selection unaffected).
// A: lane = m + 16k (xs LDS, pitch 132 -> 2-way banks). B: lane = n + 16k
// (W global, 64B/16-lane cluster, L1-resident). D val i: row 4*(l>>4)+i,
// col l&15.
__global__ __launch_bounds__(256) void encoder_mfma(
    const float* __restrict__ x, const float* __restrict__ W,
    const float* __restrict__ b, float* __restrict__ out){
  __shared__ float xs[16 * 132];   // 8448 B
  const int tid = threadIdx.x, wave = tid >> 6, lane = tid & 63;
  const size_t r0 = (size_t)blockIdx.x << 4;

  { // stage x tile: thread t -> row t/16, k-chunk (t%16)*8
    const int row = tid >> 4, k0 = (tid & 15) << 3;
    const float4* src = (const float4*)(x + ((r0 + row) << 7) + k0);
    float4 v0 = src[0], v1 = src[1];
    float* dst = xs + row * 132 + k0;
    *(float4*)(dst)     = v0;
    *(float4*)(dst + 4) = v1;
  }
  __syncthreads();

  const int ml = lane & 15, kl = lane >> 4;
  const int n0 = wave << 4;
  vdbl4 acc;
  const double bc = (double)b[n0 + ml];
  acc[0] = bc; acc[1] = bc; acc[2] = bc; acc[3] = bc;

  const float* xrow = xs + ml * 132 + kl;
  const float* wcol = W + (size_t)kl * 64 + n0 + ml;
  #pragma unroll 8
  for (int kb = 0; kb < 32; ++kb){
    double a  = (double)xrow[kb << 2];
    double bb = (double)wcol[(size_t)(kb << 2) << 6];
    acc = __builtin_amdgcn_mfma_f64_16x16x4f64(a, bb, acc, 0, 0, 0);
  }
  #pragma unroll
  for (int i = 0; i < 4; ++i){
    const size_t row = r0 + (kl << 2) + i;
    out[(row << 6) + n0 + ml] = (float)acc[i];
  }
}
#endif

// ---------------- proven encoder (round-13, bit-exact k-sequential) ----------------
__global__ __launch_bounds__(256) void encoder_v10(
    const float* __restrict__ x, const float* __restrict__ W,
    const float* __restrict__ b, float* __restrict__ out){
  __shared__ double xs64[8192];
  const int tid = threadIdx.x;
  const int w = tid >> 6, c = tid & 63;
  const size_t r0 = (size_t)blockIdx.x << 6;
  {
    const float4* xg4 = (const float4*)(x + (r0 << 7));
    #pragma unroll
    for (int s = 0; s < 8; ++s){
      const int idx = tid + (s << 8);
      float4 v = xg4[idx];
      double2 d0, d1;
      d0.x = (double)v.x; d0.y = (double)v.y;
      d1.x = (double)v.z; d1.y = (double)v.w;
      *(double2*)&xs64[(idx << 2) + 0] = d0;
      *(double2*)&xs64[(idx << 2) + 2] = d1;
    }
  }
  __syncthreads();
  double acc[16];
  const double bc = (double)b[c];
  #pragma unroll
  for (int i = 0; i < 16; ++i) acc[i] = bc;
  #pragma unroll 4
  for (int k = 0; k < 128; k += 4){
    const double w0 = (double)W[((k + 0) << 6) + c];
    const double w1 = (double)W[((k + 1) << 6) + c];
    const double w2 = (double)W[((k + 2) << 6) + c];
    const double w3 = (double)W[((k + 3) << 6) + c];
    #pragma unroll
    for (int i = 0; i < 16; ++i){
      const double2 xa = *(const double2*)&xs64[(((w << 4) + i) << 7) + k];
      const double2 xb = *(const double2*)&xs64[(((w << 4) + i) << 7) + k + 2];
      acc[i] = fma(xa.x, w0, acc[i]);
      acc[i] = fma(xa.y, w1, acc[i]);
      acc[i] = fma(xb.x, w2, acc[i]);
      acc[i] = fma(xb.y, w3, acc[i]);
    }
  }
  #pragma unroll
  for (int i = 0; i < 16; ++i)
    out[((r0 + (w << 4) + i) << 6) + c] = (float)acc[i];
}

// ---------------- edges (round-13 proven: 118 us, VGPR 28) ----------------
__global__ __launch_bounds__(256, 8) void edges_v10(
    const float* __restrict__ out32, const float* __restrict__ temp,
    float* __restrict__ rows_out, float* __restrict__ cols_out){
  __shared__ double hid[4][64];         // 2 KB
  __shared__ unsigned int cl[4][128];   // 2 KB
  const int tid = threadIdx.x, wave = tid >> 6, lane = tid & 63;
  const int gb = blockIdx.x >> 8;
  const int i0 = (blockIdx.x & 255) << 2;
  const int r  = i0 + wave;
  const float* __restrict__ og = out32 + ((size_t)gb << 16);

  hid[wave][lane] = (double)og[((size_t)r << 6) + lane];

  const unsigned int base = ((unsigned int)gb << 20) | ((unsigned int)r << 10);

  // Phase 1: bits for j = m*64 + lane, with running per-lane max
  unsigned int v[16];
  unsigned int pmax = 0u;
  #pragma unroll
  for (int m = 0; m < 16; ++m){
    const unsigned int j = (unsigned int)(m << 6) + (unsigned int)lane;
    unsigned int bits = tf_bits_part(base | j);
    v[m] = (bits & ~1023u) | (1023u - j);   // low 10 bits don't feed u
    pmax = (v[m] > pmax) ? v[m] : pmax;
  }

  // Phase 2: 16th-largest lane-max (conservative surrogate for b16)
  unsigned int sorted = bitonic32_desc(pmax, lane);
  unsigned int b16p = __shfl(sorted, 15, 64);

  // conservative cut: keep j iff z_j >= z(b16') - 1.001  (score <= z + 1)
  float u16 = __uint_as_float(0x3f800000u | (b16p >> 9)) - 1.0f;
  float z16 = -__logf(-__logf(u16));
  float uc  = __expf(-__expf(-(z16 - 1.001f)));
  unsigned int cp = ((__float_as_uint(1.0f + uc) & 0x7FFFFFu) << 9) & ~1023u;

  // Phase 3: compaction of all survivors (>=16 guaranteed since cut < b16')
  int cnt = 0;
  #pragma unroll
  for (int m = 0; m < 16; ++m) cnt += (v[m] >= cp) ? 1 : 0;
  int s = cnt;
  #pragma unroll
  for (int off = 1; off < 64; off <<= 1){
    int o = __shfl_up(s, off, 64);
    s += (lane >= off) ? o : 0;
  }
  int nc = __shfl(s, 63, 64);
  nc = (nc > 128) ? 128 : nc;
  int slot = s - cnt;
  #pragma unroll
  for (int m = 0; m < 16; ++m){
    if (v[m] >= cp && slot < 128){
      cl[wave][slot] = 1023u - (v[m] & 1023u);
      ++slot;
    }
  }

  // Phase 4: exact scoring + sort
  const double Td = (double)temp[0];
  const bool act1 = (lane < nc);
  unsigned int jc1 = act1 ? cl[wave][lane] : 0u;
  unsigned long long key = score_cand(og, &hid[wave][0], jc1, base, Td, act1);
  key = bitonic64_desc(key, lane);

  if (nc > 64){
    const int idx2 = 64 + lane;
    const bool act2 = (idx2 < nc);
    unsigned int jc2 = act2 ? cl[wave][idx2] : 0u;
    unsigned long long k2 = score_cand(og, &hid[wave][0], jc2, base, Td, act2);
    k2 = bitonic64_desc(k2, lane);
    unsigned long long kr = __shfl(k2, 63 - lane, 64);
    key = (kr > key) ? kr : key;          // elementwise top-64 (bitonic)
    #pragma unroll
    for (int j = 32; j; j >>= 1){         // descending clean
      unsigned long long o = __shfl_xor(key, j, 64);
      bool left = (lane & j) == 0;
      bool take = left ? (o > key) : (o < key);
      key = take ? o : key;
    }
  }

  const int grow = (gb << 10) + r;
  if (lane < 16){
    rows_out[((size_t)grow << 4) + lane] = (float)grow;
    cols_out[((size_t)grow << 4) + lane] =
        (float)((gb << 10) + (1023 - (int)(key & 1023ull)));
  }
}

extern "C" void kernel_launch(void* const* d_in, const int* in_sizes, int n_in,
                              void* d_out, int out_size, void* d_ws, size_t ws_size,
                              hipStream_t stream){
  const float* x = (const float*)d_in[0];
  const float* W = (const float*)d_in[1];
  const float* b = (const float*)d_in[2];
  const float* T = (const float*)d_in[3];
  float* out      = (float*)d_out;
  float* rows_out = out + OUT_ELEMS;
  float* cols_out = rows_out + EDGE_ELEMS;

#ifdef HAVE_MFMA_F64
  encoder_mfma<<<2048, 256, 0, stream>>>(x, W, b, out);
#else
  encoder_v10<<<512, 256, 0, stream>>>(x, W, b, out);
#endif
  edges_v10<<<8192, 256, 0, stream>>>(out, T, rows_out, cols_out);
}